// Round 1
// baseline (241.872 us; speedup 1.0000x reference)
//
#include <hip/hip_runtime.h>
#include <hip/hip_bf16.h>
#include <math.h>

#define B_ 256
#define D_ 32
#define E_ 30
#define H_ 128
#define S_ 101
#define BD 8192
#define NCHUNK 8
#define SPAN 13  /* ceil(101/8) */

typedef __attribute__((ext_vector_type(8))) short short8;
typedef __attribute__((ext_vector_type(4))) float f32x4;

__device__ __forceinline__ float elu1(float x) {
  return x > 0.f ? x : expm1f(x);
}
// manual RNE float->bf16 (values are finite, no NaN handling needed)
__device__ __forceinline__ short f2bf(float x) {
  unsigned int u = __float_as_uint(x);
  unsigned int r = (u + 0x7fffu + ((u >> 16) & 1u)) >> 16;
  return (short)r;
}

// ---- K0: Clenshaw-Curtis quadrature weights/steps (matches reference numerics, fp64) ----
__global__ void kquad(float* __restrict__ qw, float* __restrict__ qt) {
  int i = threadIdx.x;
  if (i > 100) return;
  const double PI = 3.14159265358979323846;
  double acc = 0.0;
  for (int j = 0; j <= 100; ++j) {
    double Wj;
    if (j == 0) Wj = 1.0;
    else if (j & 1) continue;           // W[odd] = 0
    else Wj = 2.0 / (1.0 - (double)(j * j));
    double lam;
    if (i == 0) lam = 0.5;
    else {
      lam = cos((double)(j * i) * PI / 100.0);
      if (i == 100) lam *= 0.5;
    }
    acc += lam * 0.02 * Wj;             // *2/nb_steps
  }
  qw[i] = (float)acc;
  qt[i] = (float)cos((double)i * PI / 100.0);
}

// ---- K1: h = x @ W_emb + b_emb  (256 x 960) ----
__global__ void kh(const float* __restrict__ x, const float* __restrict__ Wemb,
                   const float* __restrict__ bemb, float* __restrict__ h) {
  int o = blockIdx.x * 256 + threadIdx.x;
  if (o >= B_ * 960) return;
  int b = o / 960, c = o % 960;
  float acc = bemb[c];
  const float* xr = x + b * 32;
#pragma unroll
  for (int i = 0; i < 32; ++i) acc += xr[i] * Wemb[i * 960 + c];
  h[o] = acc;
}

// ---- K2: g[bd][j] = b1[j] + sum_e h_per[bd][e] * W1[1+e][j] ----
__global__ void kg(const float* __restrict__ h, const float* __restrict__ W1,
                   const float* __restrict__ b1, float* __restrict__ g) {
  int o = blockIdx.x * 256 + threadIdx.x;  // over 8192*128
  int bd = o >> 7, j = o & 127;
  int b = bd >> 5, d = bd & 31;
  float acc = b1[j];
#pragma unroll
  for (int e = 0; e < 30; ++e)
    acc += h[b * 960 + e * 32 + d] * W1[(1 + e) * 128 + j];
  g[o] = acc;
}

// ---- K3: pre-pack W2 into MFMA B-fragment order, bf16 ----
// layout: [n 0..7][kk 0..3][lane 0..63][e 0..7]; value = W2[k][j],
// j = 16n + (lane&15), k = 32kk + (lane>>4)*8 + e
__global__ void kwprep(const float* __restrict__ W2, unsigned short* __restrict__ w2f) {
  int t = blockIdx.x * 256 + threadIdx.x;  // 2048 threads
  int lane = t & 63;
  int kk = (t >> 6) & 3;
  int n = t >> 8;
  int j = n * 16 + (lane & 15);
  int k0 = kk * 32 + (lane >> 4) * 8;
  unsigned short* dst = w2f + (size_t)t * 8;
#pragma unroll
  for (int e = 0; e < 8; ++e)
    dst[e] = (unsigned short)f2bf(W2[(k0 + e) * 128 + j]);
}

// ---- K4: main fused kernel ----
// WG = 256 thr (4 waves, 2x2); tile = 128 bd-rows x 128 cols; loops over its s-chunk.
__launch_bounds__(256, 2)
__global__ void kmain(const float* __restrict__ x, const float* __restrict__ x0,
                      const float* __restrict__ g, const unsigned short* __restrict__ w2f,
                      const float* __restrict__ W1, const float* __restrict__ b2,
                      const float* __restrict__ W3, const float* __restrict__ b3,
                      const float* __restrict__ qw, const float* __restrict__ qt,
                      float* __restrict__ zpart) {
  __shared__ char hdn1[128 * 256];            // 128 rows x 128 bf16 (XOR-swizzled)
  __shared__ float xs[128], dxs[128], w1s[128], zacc[128];
  __shared__ float fsum[2][128];

  int tid = threadIdx.x;
  int wave = tid >> 6, lane = tid & 63;
  int wm = wave >> 1, wn = wave & 1;
  int bdt = blockIdx.x >> 3, chunk = blockIdx.x & 7;
  int bd0 = bdt * 128;
  int s0 = chunk * SPAN;
  int s1 = min(S_, s0 + SPAN);

  if (tid < 128) {
    float a0 = x0[bd0 + tid];
    xs[tid] = a0;
    dxs[tid] = x[bd0 + tid] - a0;
    w1s[tid] = W1[tid];   // W1 row 0
    zacc[tid] = 0.f;
  }
  float b3v = b3[0];

  // W2 B-fragments resident in registers (same for every tile)
  short8 bf[4][4];
#pragma unroll
  for (int nt = 0; nt < 4; ++nt)
#pragma unroll
    for (int kk = 0; kk < 4; ++kk) {
      int ng = wn * 4 + nt;
      bf[nt][kk] = *reinterpret_cast<const short8*>(w2f + (size_t)(((ng * 4 + kk) * 64 + lane) * 8));
    }
  float b2v[4], w3v[4];
#pragma unroll
  for (int nt = 0; nt < 4; ++nt) {
    int j = wn * 64 + nt * 16 + (lane & 15);
    b2v[nt] = b2[j];
    w3v[nt] = W3[j];
  }
  __syncthreads();

  const int m0 = wm * 64;
  const int row = tid >> 1;   // layer-1 row (bd offset in tile)
  const int kh = tid & 1;     // which 64-wide k half

  for (int s = s0; s < s1; ++s) {
    float cf = (qt[s] + 1.f) * 0.5f;
    float wq = qw[s];

    // ---- layer 1: hdn1 = elu(xT * W1row0 + g), bf16 into swizzled LDS ----
    {
      float xT = xs[row] + dxs[row] * cf;
      const float4* g4 = reinterpret_cast<const float4*>(g + (((size_t)(bd0 + row)) << 7) + (kh << 6));
      int swz = row & 7;
#pragma unroll
      for (int kg = 0; kg < 8; ++kg) {
        float4 a = g4[kg * 2];
        float4 b = g4[kg * 2 + 1];
        float va[8] = {a.x, a.y, a.z, a.w, b.x, b.y, b.z, b.w};
        int kbase = kh * 64 + kg * 8;
        short8 pk;
#pragma unroll
        for (int e = 0; e < 8; ++e)
          pk[e] = f2bf(elu1(va[e] + xT * w1s[kbase + e]));
        int off = row * 256 + kh * 128 + ((kg ^ swz) << 4);
        *reinterpret_cast<short8*>(hdn1 + off) = pk;
      }
    }
    __syncthreads();

    // ---- layer 2: 64x128 per wave via MFMA, W2 from registers ----
    f32x4 acc[4][4];
#pragma unroll
    for (int mt = 0; mt < 4; ++mt)
#pragma unroll
      for (int nt = 0; nt < 4; ++nt)
        acc[mt][nt] = (f32x4){0.f, 0.f, 0.f, 0.f};

#pragma unroll
    for (int kk = 0; kk < 4; ++kk) {
      short8 af[4];
#pragma unroll
      for (int mt = 0; mt < 4; ++mt) {
        int arow = m0 + mt * 16 + (lane & 15);
        int off = (arow * 256 + kk * 64 + ((lane >> 4) << 4)) ^ ((arow & 7) << 4);
        af[mt] = *reinterpret_cast<const short8*>(hdn1 + off);
      }
#pragma unroll
      for (int mt = 0; mt < 4; ++mt)
#pragma unroll
        for (int nt = 0; nt < 4; ++nt)
          acc[mt][nt] = __builtin_amdgcn_mfma_f32_16x16x32_bf16(af[mt], bf[nt][kk], acc[mt][nt], 0, 0, 0);
    }

    // ---- layer 3: f-partials = sum_j elu(hdn2 + b2) * W3, reduce 16 lanes ----
#pragma unroll
    for (int mt = 0; mt < 4; ++mt) {
#pragma unroll
      for (int r = 0; r < 4; ++r) {
        float sm = 0.f;
#pragma unroll
        for (int nt = 0; nt < 4; ++nt) {
          float h2 = acc[mt][nt][r] + b2v[nt];
          sm += elu1(h2) * w3v[nt];
        }
        sm += __shfl_xor(sm, 1);
        sm += __shfl_xor(sm, 2);
        sm += __shfl_xor(sm, 4);
        sm += __shfl_xor(sm, 8);
        if ((lane & 15) == 0)
          fsum[wn][m0 + mt * 16 + ((lane >> 4) << 2) + r] = sm;
      }
    }
    __syncthreads();

    // ---- combine halves, elu+1, weighted accumulate ----
    if (tid < 128) {
      float fs = fsum[0][tid] + fsum[1][tid] + b3v;
      zacc[tid] += wq * (elu1(fs) + 1.f);
    }
  }

  if (tid < 128) zpart[(size_t)chunk * BD + bd0 + tid] = zacc[tid];
}

// ---- K5: reduce chunks, scale, add z0 ----
__global__ void kfinal(const float* __restrict__ zpart, const float* __restrict__ x,
                       const float* __restrict__ x0, const float* __restrict__ h,
                       const float* __restrict__ scaling, float* __restrict__ out) {
  int bd = blockIdx.x * 256 + threadIdx.x;
  if (bd >= BD) return;
  float zs = 0.f;
#pragma unroll
  for (int c = 0; c < NCHUNK; ++c) zs += zpart[(size_t)c * BD + bd];
  int b = bd >> 5, d = bd & 31;
  float z0 = h[b * 960 + d];
  out[bd] = expf(scaling[d]) * (0.5f * (x[bd] - x0[bd]) * zs + z0);
}

extern "C" void kernel_launch(void* const* d_in, const int* in_sizes, int n_in,
                              void* d_out, int out_size, void* d_ws, size_t ws_size,
                              hipStream_t stream) {
  const float* x       = (const float*)d_in[0];
  const float* x0      = (const float*)d_in[1];
  const float* Wemb    = (const float*)d_in[2];
  const float* bemb    = (const float*)d_in[3];
  const float* W1      = (const float*)d_in[4];
  const float* b1      = (const float*)d_in[5];
  const float* W2      = (const float*)d_in[6];
  const float* b2      = (const float*)d_in[7];
  const float* W3      = (const float*)d_in[8];
  const float* b3      = (const float*)d_in[9];
  const float* scaling = (const float*)d_in[10];

  float* ws = (float*)d_ws;
  float* qw = ws;                                   // 128
  float* qt = ws + 128;                             // 128
  float* h  = ws + 256;                             // 256*960 = 245760
  float* g  = ws + 246016;                          // 8192*128 = 1048576
  unsigned short* w2f = (unsigned short*)(ws + 1294592);  // 16384 bf16 = 8192 floats
  float* zpart = ws + 1302784;                      // 8*8192 = 65536
  float* out = (float*)d_out;

  hipLaunchKernelGGL(kquad, dim3(1), dim3(128), 0, stream, qw, qt);
  hipLaunchKernelGGL(kh, dim3(960), dim3(256), 0, stream, x, Wemb, bemb, h);
  hipLaunchKernelGGL(kg, dim3(4096), dim3(256), 0, stream, h, W1, b1, g);
  hipLaunchKernelGGL(kwprep, dim3(8), dim3(256), 0, stream, W2, w2f);
  hipLaunchKernelGGL(kmain, dim3(512), dim3(256), 0, stream,
                     x, x0, g, w2f, W1, b2, W3, b3, qw, qt, zpart);
  hipLaunchKernelGGL(kfinal, dim3(32), dim3(256), 0, stream,
                     zpart, x, x0, h, scaling, out);
}